// Round 3
// baseline (2222.529 us; speedup 1.0000x reference)
//
#include <hip/hip_runtime.h>
#include <cstdint>
#include <cstddef>

#define T_LEN 2048
#define B_SZ 4
#define C_CH 512
#define H_N 8
#define DK_ 64
#define FC_CH 2048
#define L_N 6
#define KW 3
#define S_CH 256

typedef _Float16 h8 __attribute__((ext_vector_type(8)));
typedef _Float16 h4 __attribute__((ext_vector_type(4)));
typedef float floatx4 __attribute__((ext_vector_type(4)));

// ---------------------------------------------------------------------------
// Weight prepack kernels (run every call; weights -> f16 in ws).
// ---------------------------------------------------------------------------
__global__ __launch_bounds__(256)
void cast_f16(const float* __restrict__ src, _Float16* __restrict__ dst, int n)
{
    int i = blockIdx.x * 256 + threadIdx.x;
    if (i < n) dst[i] = (_Float16)src[i];
}

// src [row][c][k] (k fastest, K=3) -> dst [row][c0blk][k][cl] (32-ch chunks)
// 2D grid (col-chunk, row) so ALL divisors are compile-time consts.
__global__ __launch_bounds__(256)
void prepack_k3(const float* __restrict__ src, _Float16* __restrict__ dst, int rk)
{
    const int o = blockIdx.x * 256 + threadIdx.x;
    if (o >= rk) return;
    const size_t row = blockIdx.y;
    const int blk = o / 96, rr = o - blk * 96;   // 96 = const -> magic mul
    const int k = rr >> 5, cl = rr & 31;
    dst[row * rk + o] = (_Float16)src[row * rk + (size_t)(blk * 32 + cl) * 3 + k];
}

// concat q|k|v weights into [l][1536][512] f16 + biases into [l][1536] f32
__global__ __launch_bounds__(256)
void prepack_qkv(const float* __restrict__ qw, const float* __restrict__ kw,
                 const float* __restrict__ vw, const float* __restrict__ qb,
                 const float* __restrict__ kb, const float* __restrict__ vb,
                 _Float16* __restrict__ dst, float* __restrict__ bdst)
{
    int i = blockIdx.x * 256 + threadIdx.x;
    const int total = L_N * 1536 * 512;
    if (i < total) {
        int l = i / (1536 * 512);
        int o = i - l * (1536 * 512);
        int m = o >> 9, c = o & 511;
        const float* s = (m < 512) ? qw : ((m < 1024) ? kw : vw);
        dst[i] = (_Float16)s[((size_t)l * 512 + (m & 511)) * 512 + c];
    }
    if (i < L_N * 1536) {
        int l = i / 1536, m = i - l * 1536;
        const float* s = (m < 512) ? qb : ((m < 1024) ? kb : vb);
        bdst[i] = s[l * 512 + (m & 511)];
    }
}

// ---------------------------------------------------------------------------
// Transpose [b][Cd][T] -> f16 [b][T][Cd], optionally fusing the f0 conv add.
// ---------------------------------------------------------------------------
__global__ __launch_bounds__(256)
void transpose_f0(const float* __restrict__ src, _Float16* __restrict__ dst, int Cd,
                  const float* __restrict__ nf0, const float* __restrict__ f0w,
                  const float* __restrict__ f0b, int do_f0)
{
    __shared__ float tile[32][33];
    const int tl = threadIdx.x & 31;
    const int r  = threadIdx.x >> 5;
    const int t00 = blockIdx.x * 32;
    const int c00 = blockIdx.y * 32;
    const int b   = blockIdx.z;
    const float* s0 = src + (size_t)b * Cd * T_LEN;
#pragma unroll
    for (int rr = 0; rr < 4; ++rr) {
        int cl = r + rr * 8;
        tile[cl][tl] = s0[(size_t)(c00 + cl) * T_LEN + t00 + tl];
    }
    __syncthreads();
    _Float16* d0 = dst + (size_t)b * T_LEN * Cd;
    const int cg = c00 + tl;
#pragma unroll
    for (int rr = 0; rr < 4; ++rr) {
        int tlo = r + rr * 8;
        float v = tile[tl][tlo];
        if (do_f0) {
            int tg = t00 + tlo;
            float a = f0b[cg];
#pragma unroll
            for (int k = 0; k < 3; ++k) {
                int gt = tg + k - 1;
                if (gt >= 0 && gt < T_LEN) a += f0w[cg * 3 + k] * nf0[(size_t)b * T_LEN + gt];
            }
            v += a;
        }
        d0[(size_t)(t00 + tlo) * Cd + cg] = (_Float16)v;
    }
}

// ---------------------------------------------------------------------------
// Conv1d-as-GEMM on MFMA, prepacked f16 weights, f16 activations.
//
// Round-10 restructure (ffn2 counters: MfmaUtil 20%, Occ 21% — per-chunk
// critical path was barrier+write+barrier+read): DOUBLE-BUFFERED LDS with ONE
// barrier per chunk. While computing chunk c from buf[c&1], stage chunk c+1
// into buf[(c+1)&1]. Sec-0 ds_reads are issued BEFORE the stage ds_writes:
// DS ops retire in order, so the lgkmcnt wait for sec-0 fragments does not
// drain the writes — staging completes under the MFMA stream.
//
// Register pipeline unchanged: A 1-deep prefetch (areg), B 2-deep with
// statically-named breg0/breg1 (round-7 lesson: a runtime-indexed register
// array demotes to scratch, ~13x cost; the LDS buffer index pb is only an
// address offset, which is safe). All call sites have even nch >= 4.
//
// MT=64 everywhere: LDS/buf KK=3 = 23.9KB (x2 = 47.7KB, 3 blocks/CU cap),
// KK=1 = 27.6KB (x2 = 55.3KB, 2 blocks/CU cap). Both < 64KB/WG limit.
//
// OUTMODE: 1 = f16 [b][t][out_stride] (+res); 3 = fused QKV (m0<1024 -> out_v
// stride 1024; m0>=1024 -> out2 transposed [b][m-1024][t]).
// ---------------------------------------------------------------------------
template<int KK, int OUTMODE, int MT>
__global__ __launch_bounds__(256)
void conv_gemm_mfma(const _Float16* __restrict__ in, const _Float16* __restrict__ Wpk,
                    const float* __restrict__ bias, const _Float16* __restrict__ res,
                    const float* __restrict__ mask, _Float16* __restrict__ out_v,
                    _Float16* __restrict__ out2,
                    int Cin, int out_stride, int pl, int do_relu,
                    int mask_in, int mask_out)
{
    constexpr int CS   = (KK == 3) ? 32 : 64;   // channels per chunk
    constexpr int NSEC = (KK == 3) ? 3 : 2;     // 32-wide A sections
    constexpr int AST  = NSEC * 32 + 8;         // 104 / 72 halves
    constexpr int HALO = (KK == 3) ? 2 : 0;
    constexpr int RB   = 128 + 2 * HALO;
    constexpr int BST  = CS + 8;                // 40 / 72 halves
    constexpr int NAH  = NSEC * MT / 64;        // A h8-regs per thread
    constexpr int SEGW = NSEC * MT / 8;         // A halves per staging segment
    constexpr int IM_N = MT / 32;               // acc M-frags per wave
    constexpr int NTASK = RB * (CS / 16);       // B 16-half tasks
    __shared__ _Float16 sA[2][MT * AST];
    __shared__ _Float16 sB[2][RB * BST];

    const int tid = threadIdx.x;
    const int lane = tid & 63;
    const int wid = tid >> 6;
    const int wm = wid >> 1, wt = wid & 1;
    const int r = lane & 15, q4 = lane >> 4;
    const int t0 = blockIdx.x * 128;
    const int m0 = blockIdx.y * MT;
    const int b  = blockIdx.z;
    const float* mk = mask + (size_t)b * T_LEN;

    floatx4 acc[IM_N][4];
#pragma unroll
    for (int i = 0; i < IM_N; ++i)
#pragma unroll
        for (int j = 0; j < 4; ++j)
#pragma unroll
            for (int c = 0; c < 4; ++c) acc[i][j][c] = 0.f;

    // ---- A staging assignment (bank-conflict-free writes) ----
    const int arow = tid & (MT - 1);
    const int ah0  = (tid / MT) * SEGW;
    const _Float16* ap = Wpk + (size_t)(m0 + arow) * Cin * KK + ah0;

    // ---- B task decode (chunk-invariant) ----
    int brw[2], bcc[2];
    bool bex[2], bval[2];
    _Float16 bm[2];
    const _Float16* bq[2];
    h8 areg[NAH], breg0[2][2], breg1[2][2];   // [task][half], buffers statically named
#pragma unroll
    for (int t2 = 0; t2 < 2; ++t2) {
        const int id = tid + t2 * 256;
        bex[t2] = (id < NTASK);
        int row, c16;
        if (KK == 3) { row = id % RB; c16 = (id / RB) * 16; }
        else         { row = id >> 2; c16 = (id & 3) * 16; }
        const int gt = t0 + row - HALO;
        bval[t2] = bex[t2] && gt >= 0 && gt < T_LEN;
        brw[t2] = row; bcc[t2] = c16;
        bm[t2] = (_Float16)((bval[t2] && mask_in) ? mk[gt] : 1.f);
        bq[t2] = in + (size_t)b * T_LEN * Cin + (size_t)gt * Cin + c16;
#pragma unroll
        for (int hh = 0; hh < 2; ++hh)
#pragma unroll
            for (int j = 0; j < 8; ++j) {
                breg0[t2][hh][j] = (_Float16)0.f;
                breg1[t2][hh][j] = (_Float16)0.f;
            }
    }
    const int nch = Cin / CS;   // even, >= 4, for all call sites

    // helpers (all fully inlined; static unrolls inside)
    auto loadA = [&]() {                 // areg <- next A chunk
        ap += CS * KK;
#pragma unroll
        for (int j = 0; j < NAH; ++j) areg[j] = *reinterpret_cast<const h8*>(ap + j * 8);
    };
    auto loadB = [&](h8 (&br)[2][2]) {   // br <- next B chunk (2-deep queue)
#pragma unroll
        for (int t2 = 0; t2 < 2; ++t2)
            if (bval[t2]) {
                br[t2][0] = *reinterpret_cast<const h8*>(bq[t2]);
                br[t2][1] = *reinterpret_cast<const h8*>(bq[t2] + 8);
                bq[t2] += CS;
            }
    };
    auto stage = [&](int pb, h8 (&br)[2][2]) {   // regs -> LDS buf pb
#pragma unroll
        for (int j = 0; j < NAH; ++j)
            *reinterpret_cast<h8*>(&sA[pb][arow * AST + ah0 + j * 8]) = areg[j];
#pragma unroll
        for (int t2 = 0; t2 < 2; ++t2)
            if (bex[t2]) {
                *reinterpret_cast<h8*>(&sB[pb][brw[t2] * BST + bcc[t2]]) = br[t2][0] * bm[t2];
                *reinterpret_cast<h8*>(&sB[pb][brw[t2] * BST + bcc[t2] + 8]) = br[t2][1] * bm[t2];
            }
    };

    // ---- prologue: A(0)->areg, B(0)->breg0, B(1)->breg1; stage chunk 0 ----
#pragma unroll
    for (int j = 0; j < NAH; ++j) areg[j] = *reinterpret_cast<const h8*>(ap + j * 8);
#pragma unroll
    for (int t2 = 0; t2 < 2; ++t2)
        if (bval[t2]) {
            breg0[t2][0] = *reinterpret_cast<const h8*>(bq[t2]);
            breg0[t2][1] = *reinterpret_cast<const h8*>(bq[t2] + 8);
            breg1[t2][0] = *reinterpret_cast<const h8*>(bq[t2] + CS);
            breg1[t2][1] = *reinterpret_cast<const h8*>(bq[t2] + CS + 8);
            bq[t2] += 2 * CS;
        }
    stage(0, breg0);                 // chunk 0 -> buf0 (no barrier needed first)
    loadA();                         // areg = A(1)
    loadB(breg0);                    // breg0 = B(2)
    __syncthreads();                 // buf0 ready

    // one body: compute chunk cc from buf pb; stage chunk cc+1 (areg + br)
    // into buf pb^1; prefetch A(cc+2) and B(cc+3)->br. ONE barrier at end.
    auto body = [&](int pb, int cc, h8 (&br)[2][2]) {
        // sec-0 fragment reads FIRST (in-order lgkm retirement: sec-0 MFMAs
        // wait only for these, not for the stage writes issued after)
        h8 af0[IM_N], bf0[4];
#pragma unroll
        for (int im = 0; im < IM_N; ++im)
            af0[im] = *reinterpret_cast<const h8*>(&sA[pb][(wm * (MT / 2) + im * 16 + r) * AST + q4 * 8]);
        {
            const int rb0 = (KK == 3) ? (wt * 64 + r - pl + HALO) : (wt * 64 + r);
#pragma unroll
            for (int jt = 0; jt < 4; ++jt)
                bf0[jt] = *reinterpret_cast<const h8*>(&sB[pb][(rb0 + jt * 16) * BST + q4 * 8]);
        }
        if (cc + 1 < nch) stage(pb ^ 1, br);
        if (cc + 2 < nch) loadA();
        if (cc + 3 < nch) loadB(br);
#pragma unroll
        for (int im = 0; im < IM_N; ++im)
#pragma unroll
            for (int jt = 0; jt < 4; ++jt)
                acc[im][jt] = __builtin_amdgcn_mfma_f32_16x16x32_f16(af0[im], bf0[jt], acc[im][jt], 0, 0, 0);
#pragma unroll
        for (int sec = 1; sec < NSEC; ++sec) {
            h8 af[IM_N], bf[4];
#pragma unroll
            for (int im = 0; im < IM_N; ++im)
                af[im] = *reinterpret_cast<const h8*>(&sA[pb][(wm * (MT / 2) + im * 16 + r) * AST + sec * 32 + q4 * 8]);
            const int rb0 = (KK == 3) ? (wt * 64 + r + sec - pl + HALO) : (wt * 64 + r);
            const int cb0 = (KK == 3) ? 0 : sec * 32;
#pragma unroll
            for (int jt = 0; jt < 4; ++jt)
                bf[jt] = *reinterpret_cast<const h8*>(&sB[pb][(rb0 + jt * 16) * BST + cb0 + q4 * 8]);
#pragma unroll
            for (int im = 0; im < IM_N; ++im)
#pragma unroll
                for (int jt = 0; jt < 4; ++jt)
                    acc[im][jt] = __builtin_amdgcn_mfma_f32_16x16x32_f16(af[im], bf[jt], acc[im][jt], 0, 0, 0);
        }
        __syncthreads();
    };

    for (int ci = 0; ci < nch; ci += 2) {
        body(0, ci, breg1);          // chunk ci   (even -> buf0; stages odd)
        body(1, ci + 1, breg0);      // chunk ci+1 (odd -> buf1; stages even)
    }

    // ---- epilogue: D row = m (q4*4+reg), col = t (r) ----
#pragma unroll
    for (int im = 0; im < IM_N; ++im) {
        const int mb = m0 + wm * (MT / 2) + im * 16 + q4 * 4;
        const float4 bv = *reinterpret_cast<const float4*>(&bias[mb]);
#pragma unroll
        for (int jt = 0; jt < 4; ++jt) {
            const int t = t0 + wt * 64 + jt * 16 + r;
            float vv[4];
            vv[0] = acc[im][jt][0] + bv.x;
            vv[1] = acc[im][jt][1] + bv.y;
            vv[2] = acc[im][jt][2] + bv.z;
            vv[3] = acc[im][jt][3] + bv.w;
            if (do_relu) {
#pragma unroll
                for (int c = 0; c < 4; ++c) vv[c] = fmaxf(vv[c], 0.f);
            }
            if (mask_out) {
                const float mv = mk[t];
#pragma unroll
                for (int c = 0; c < 4; ++c) vv[c] *= mv;
            }
            if (OUTMODE == 1) {
                const size_t ob = ((size_t)b * T_LEN + t) * out_stride + mb;
                if (res) {
                    const h4 rv = *reinterpret_cast<const h4*>(&res[ob]);
#pragma unroll
                    for (int c = 0; c < 4; ++c) vv[c] += (float)rv[c];
                }
                h4 hv;
#pragma unroll
                for (int c = 0; c < 4; ++c) hv[c] = (_Float16)vv[c];
                *reinterpret_cast<h4*>(&out_v[ob]) = hv;
            } else {   // fused QKV
                if (m0 < 1024) {
                    const size_t ob = ((size_t)b * T_LEN + t) * 1024 + mb;
                    h4 hv;
#pragma unroll
                    for (int c = 0; c < 4; ++c) hv[c] = (_Float16)vv[c];
                    *reinterpret_cast<h4*>(&out_v[ob]) = hv;
                } else {
#pragma unroll
                    for (int reg = 0; reg < 4; ++reg)
                        out2[((size_t)b * C_CH + (mb - 1024) + reg) * T_LEN + t] = (_Float16)vv[reg];
                }
            }
        }
    }
}

// ---------------------------------------------------------------------------
// MFMA flash attention with ONLINE softmax (p <= 1, f16-safe).
// qk: [b][t][1024] f16 (q|k); vt: [b][h*64+d][t] f16; o: [b][t][512] f16.
// Q-tile 64, swapped QK^T (lane-resident softmax rows), h4 P stores.
// blockIdx.x reversed: longest (qt0 max) first.
// ---------------------------------------------------------------------------
__global__ __launch_bounds__(256)
void flash_attn_mfma(const _Float16* __restrict__ qk, const _Float16* __restrict__ vt,
                     _Float16* __restrict__ o)
{
    __shared__ _Float16 sK[64 * 72];    // [s][d]
    __shared__ _Float16 sVt[64 * 72];   // [d][s]
    __shared__ _Float16 sP[64 * 72];    // [q][s]
    const int tid = threadIdx.x;
    const int lane = tid & 63;
    const int w = tid >> 6;             // wave w owns q rows qt0+w*16 .. +15
    const int r = lane & 15, q4 = lane >> 4;
    const int qt0 = (int)(31 - blockIdx.x) * 64;
    const int h = blockIdx.y, b = blockIdx.z;
    const size_t tb = (size_t)b * T_LEN;
    const int hq = h * 64, hk = 512 + h * 64;
    const _Float16* vbase = vt + ((size_t)b * C_CH + h * 64) * T_LEN;

    // Q fragment (B-operand: lane holds col n=r -> q-row qt0+w*16+r, k=q4*8+j)
    h8 qf[2];
#pragma unroll
    for (int dc = 0; dc < 2; ++dc) {
        h8 t = *reinterpret_cast<const h8*>(
            &qk[(tb + qt0 + w * 16 + r) * 1024 + hq + dc * 32 + q4 * 8]);
        qf[dc] = t * (_Float16)0.125f;
    }

    floatx4 oacc[4];
    float mrow = -__builtin_inff();     // running max for q-row qt0+w*16+r
    float lrow = 0.f;                   // running sum for q-row qt0+w*16+r
#pragma unroll
    for (int jd = 0; jd < 4; ++jd)
#pragma unroll
        for (int c = 0; c < 4; ++c) oacc[jd][c] = 0.f;

    const int qg = qt0 + w * 16 + r;    // this lane's q-row (for mask + softmax)
    const int nk = (qt0 >> 6) + 1;
    for (int kt = 0; kt < nk; ++kt) {
        const int kt0 = kt * 64;
        __syncthreads();
        {   // stage K tile [64 s][64 d]
            int row = tid >> 2, c16 = (tid & 3) * 16;
            const _Float16* src = &qk[(tb + kt0 + row) * 1024 + hk + c16];
            *reinterpret_cast<h8*>(&sK[row * 72 + c16]) = *reinterpret_cast<const h8*>(src);
            *reinterpret_cast<h8*>(&sK[row * 72 + c16 + 8]) = *reinterpret_cast<const h8*>(src + 8);
        }
#pragma unroll
        for (int p = 0; p < 2; ++p) {   // stage V^T tile [64 d][64 s]
            int id = p * 256 + tid;
            int d = id >> 3, s8 = (id & 7) * 8;
            *reinterpret_cast<h8*>(&sVt[d * 72 + s8]) =
                *reinterpret_cast<const h8*>(&vbase[(size_t)d * T_LEN + kt0 + s8]);
        }
        __syncthreads();

        // ---- QK^T (swapped): sacc[js] holds D[s=kt0+js*16+q4*4+reg][q=qg]
        floatx4 sacc[4];
#pragma unroll
        for (int js = 0; js < 4; ++js)
#pragma unroll
            for (int c = 0; c < 4; ++c) sacc[js][c] = 0.f;
#pragma unroll
        for (int dc = 0; dc < 2; ++dc) {
            h8 kf[4];
#pragma unroll
            for (int js = 0; js < 4; ++js)
                kf[js] = *reinterpret_cast<const h8*>(&sK[(js * 16 + r) * 72 + dc * 32 + q4 * 8]);
#pragma unroll
            for (int js = 0; js < 4; ++js)
                sacc[js] = __builtin_amdgcn_mfma_f32_16x16x32_f16(kf[js], qf[dc], sacc[js], 0, 0, 0);
        }
        // ---- causal mask (s > q -> -1e4, matches reference where())
#pragma unroll
        for (int js = 0; js < 4; ++js) {
            const int sb = kt0 + js * 16 + q4 * 4;
#pragma unroll
            for (int reg = 0; reg < 4; ++reg)
                if (sb + reg > qg) sacc[js][reg] = -1e4f;
        }
        // ---- row max: 16 in-register values, then cross-q4-group reduce
        float mt;
        {
            float a = fmaxf(fmaxf(sacc[0][0], sacc[0][1]), fmaxf(sacc[0][2], sacc[0][3]));
            float bm = fmaxf(fmaxf(sacc[1][0], sacc[1][1]), fmaxf(sacc[1][2], sacc[1][3]));
            float c = fmaxf(fmaxf(sacc[2][0], sacc[2][1]), fmaxf(sacc[2][2], sacc[2][3]));
            float d = fmaxf(fmaxf(sacc[3][0], sacc[3][1]), fmaxf(sacc[3][2], sacc[3][3]));
            mt = fmaxf(fmaxf(a, bm), fmaxf(c, d));
        }
        mt = fmaxf(mt, __shfl_xor(mt, 16));
        mt = fmaxf(mt, __shfl_xor(mt, 32));
        const float mn = fmaxf(mrow, mt);
        const float alpha = __expf(mrow - mn);
        mrow = mn;
        // ---- P = exp(s - mn), in-register row sum
        float rs = 0.f;
#pragma unroll
        for (int js = 0; js < 4; ++js)
#pragma unroll
            for (int reg = 0; reg < 4; ++reg) {
                float p = __expf(sacc[js][reg] - mn);
                sacc[js][reg] = p;
                rs += p;
            }
        rs += __shfl_xor(rs, 16);
        rs += __shfl_xor(rs, 32);
        lrow = lrow * alpha + rs;
        // ---- rescale O accumulator (row layout q = w*16 + q4*4 + reg)
        float ao[4];
#pragma unroll
        for (int reg = 0; reg < 4; ++reg) ao[reg] = __shfl(alpha, (q4 << 2) + reg, 16);
#pragma unroll
        for (int jd = 0; jd < 4; ++jd)
#pragma unroll
            for (int reg = 0; reg < 4; ++reg) oacc[jd][reg] *= ao[reg];
        // ---- P -> LDS, vectorized h4 (regs are s-contiguous in swapped layout)
#pragma unroll
        for (int js = 0; js < 4; ++js) {
            h4 hv;
#pragma unroll
            for (int reg = 0; reg < 4; ++reg) hv[reg] = (_Float16)sacc[js][reg];
            *reinterpret_cast<h4*>(&sP[(w * 16 + r) * 72 + js * 16 + q4 * 4]) = hv;
        }
        // ---- PV: oacc[jd] += P[q][s] * V[s][d]   (same-wave sP reuse, no barrier)
#pragma unroll
        for (int sc = 0; sc < 2; ++sc) {
            h8 pf = *reinterpret_cast<const h8*>(&sP[(w * 16 + r) * 72 + sc * 32 + q4 * 8]);
            h8 vf[4];
#pragma unroll
            for (int jd = 0; jd < 4; ++jd)
                vf[jd] = *reinterpret_cast<const h8*>(&sVt[(jd * 16 + r) * 72 + sc * 32 + q4 * 8]);
#pragma unroll
            for (int jd = 0; jd < 4; ++jd)
                oacc[jd] = __builtin_amdgcn_mfma_f32_16x16x32_f16(pf, vf[jd], oacc[jd], 0, 0, 0);
        }
    }
    // ---- epilogue: O row q = qt0 + w*16 + q4*4 + reg, col d = jd*16 + r
    const float linv = 1.f / lrow;      // for q-row = qg (lane layout q=r)
    float li[4];
#pragma unroll
    for (int reg = 0; reg < 4; ++reg) li[reg] = __shfl(linv, (q4 << 2) + reg, 16);
#pragma unroll
    for (int reg = 0; reg < 4; ++reg) {
        const size_t rowb = (tb + qt0 + w * 16 + (q4 << 2) + reg) * 512 + h * 64 + r;
#pragma unroll
        for (int jd = 0; jd < 4; ++jd)
            o[rowb + jd * 16] = (_Float16)(oacc[jd][reg] * li[reg]);
    }
}

// ---------------------------------------------------------------------------
// Channel LayerNorm on f16 [b][t][512]: one wave per t-row. outx = LN(x+y)*g+be
// ---------------------------------------------------------------------------
__global__ __launch_bounds__(256)
void ln_kernel(const _Float16* __restrict__ x, const _Float16* __restrict__ y,
               const float* __restrict__ g, const float* __restrict__ be,
               _Float16* __restrict__ outx)
{
    const int w = threadIdx.x >> 6, lane = threadIdx.x & 63;
    const int t = blockIdx.x * 4 + w, b = blockIdx.y;
    const size_t base = ((size_t)b * T_LEN + t) * C_CH + lane * 8;
    h8 xv = *reinterpret_cast<const h8*>(&x[base]);
    h8 yv = *reinterpret_cast<const h8*>(&y[base]);
    float v[8];
#pragma unroll
    for (int i = 0; i < 8; ++i) v[i] = (float)xv[i] + (float)yv[i];
    float s = 0.f, s2 = 0.f;
#pragma unroll
    for (int i = 0; i < 8; ++i) { s += v[i]; s2 += v[i] * v[i]; }
#pragma unroll
    for (int off = 1; off < 64; off <<= 1) {
        s  += __shfl_xor(s, off);
        s2 += __shfl_xor(s2, off);
    }
    const float mean = s * (1.f / C_CH);
    const float var  = s2 * (1.f / C_CH) - mean * mean;
    const float rstd = rsqrtf(var + 1e-5f);
    float4 g0 = *reinterpret_cast<const float4*>(&g[lane * 8]);
    float4 g1 = *reinterpret_cast<const float4*>(&g[lane * 8 + 4]);
    float4 b0 = *reinterpret_cast<const float4*>(&be[lane * 8]);
    float4 b1 = *reinterpret_cast<const float4*>(&be[lane * 8 + 4]);
    const float gg[8] = {g0.x, g0.y, g0.z, g0.w, g1.x, g1.y, g1.z, g1.w};
    const float bb[8] = {b0.x, b0.y, b0.z, b0.w, b1.x, b1.y, b1.z, b1.w};
    h8 ov;
#pragma unroll
    for (int i = 0; i < 8; ++i)
        ov[i] = (_Float16)((v[i] - mean) * rstd * gg[i] + bb[i]);
    *reinterpret_cast<h8*>(&outx[base]) = ov;
}

// out[b,t] = ( mask * sum_c pw[c]*x[b,t,c] + pb ) * mask   (one wave per t)
__global__ __launch_bounds__(256)
void proj_kernel(const _Float16* __restrict__ x, const float* __restrict__ pw,
                 const float* __restrict__ pb, const float* __restrict__ mask,
                 float* __restrict__ out)
{
    const int w = threadIdx.x >> 6, lane = threadIdx.x & 63;
    const int t = blockIdx.x * 4 + w, b = blockIdx.y;
    const size_t base = ((size_t)b * T_LEN + t) * C_CH + lane * 8;
    h8 xv = *reinterpret_cast<const h8*>(&x[base]);
    float4 p0 = *reinterpret_cast<const float4*>(&pw[lane * 8]);
    float4 p1 = *reinterpret_cast<const float4*>(&pw[lane * 8 + 4]);
    const float pp[8] = {p0.x, p0.y, p0.z, p0.w, p1.x, p1.y, p1.z, p1.w};
    float s = 0.f;
#pragma unroll
    for (int i = 0; i < 8; ++i) s += (float)xv[i] * pp[i];
#pragma unroll
    for (int off = 1; off < 64; off <<= 1) s += __shfl_xor(s, off);
    if (lane == 0) {
        const float mv = mask[(size_t)b * T_LEN + t];
        out[(size_t)b * T_LEN + t] = (s * mv + pb[0]) * mv;
    }
}

extern "C" void kernel_launch(void* const* d_in, const int* in_sizes, int n_in,
                              void* d_out, int out_size, void* d_ws, size_t ws_size,
                              hipStream_t stream)
{
    const float* x    = (const float*)d_in[0];
    const float* nf0  = (const float*)d_in[1];
    const float* xm   = (const float*)d_in[2];
    const float* spk  = (const float*)d_in[3];
    const float* prw  = (const float*)d_in[4];
    const float* prb  = (const float*)d_in[5];
    const float* f0w  = (const float*)d_in[6];
    const float* f0b  = (const float*)d_in[7];
    const float* cw   = (const float*)d_in[8];
    const float* cb   = (const float*)d_in[9];
    const float* pjw  = (const float*)d_in[10];
    const float* pjb  = (const float*)d_in[11];
    const float* qw   = (const float*)d_in[12];
    const float* qb   = (const float*)d_in[13];
    const float* kw   = (const float*)d_in[14];
    const float* kb   = (const float*)d_in[15];
    const float* vw   = (const float*)d_in[16];
    const float* vb   = (const float*)d_in[17];
    const float* ow   = (const float*)d_in[18];
    const float* ob   = (const float*)d_in[19];
    const float* ln0g = (const float*)d_in[20];
    const float* ln0b = (const float*)d_in[21];
    const float* ln1g = (const float*)d_in[22];
    const float* ln1b = (const float*)d_in[23];
    const float* f1w  = (const float*)d_in[24];
    const float* f1b  = (const float*)d_in[25];
    const float* f2w  = (const float*)d_in[26];
    const float* f2b  = (const float*)d_in[27];
    float* out = (float*)d_out;

    const size_t NCT = (size_t)B_SZ * C_CH * T_LEN;
    char* wp = (char*)d_ws;
    _Float16* xbuf = (_Float16*)wp; wp += NCT * 2;            // [b][t][512] residual
    _Float16* t0h  = (_Float16*)wp; wp += NCT * 2;            // [b][t][512] sublayer out
    _Float16* qk   = (_Float16*)wp; wp += NCT * 4;            // [b][t][1024]
    _Float16* vt   = (_Float16*)wp; wp += NCT * 2;            // [b][h*64+d][t]
    _Float16* obf  = (_Float16*)wp; wp += NCT * 2;            // [b][t][512]
    _Float16* h1   = (_Float16*)wp; wp += NCT * 8;            // [b][t][2048]
    _Float16* xT   = h1;                                       // alias (dead before h1 use)
    _Float16* spkT = obf;                                      // alias (dead before obf use)
    _Float16* Wqkv = (_Float16*)wp; wp += (size_t)L_N * 1536 * 512 * 2;
    _Float16* Wo   = (_Float16*)wp; wp += (size_t)L_N * 512 * 512 * 2;
    _Float16* Wcnd = (_Float16*)wp; wp += (size_t)512 * 256 * 2;
    _Float16* Wpre = (_Float16*)wp; wp += (size_t)512 * 512 * 3 * 2;
    _Float16* Wf1  = (_Float16*)wp; wp += (size_t)L_N * 2048 * 512 * 3 * 2;
    _Float16* Wf2  = (_Float16*)wp; wp += (size_t)L_N * 512 * 2048 * 3 * 2;
    float*    Bqkv = (float*)wp;    wp += (size_t)L_N * 1536 * 4;

    dim3 blk(256);
    dim3 gC64(16, 8, B_SZ);     // M=512 convs, MT=64
    dim3 gQKV(16, 24, B_SZ);    // M=1536 fused QKV, MT=64
    dim3 gF(16, 32, B_SZ);      // M=2048 ffn1, MT=64
    dim3 gAT(32, H_N, B_SZ);    // flash, Q-tile 64
    dim3 gLN(T_LEN / 4, B_SZ);

    // ---- weight prepack ----
    {
        int n;
        n = C_CH * S_CH;       cast_f16<<<(n + 255) / 256, blk, 0, stream>>>(cw, Wcnd, n);
        n = L_N * C_CH * C_CH; cast_f16<<<(n + 255) / 256, blk, 0, stream>>>(ow, Wo, n);
        prepack_k3<<<dim3(6, C_CH), blk, 0, stream>>>(prw, Wpre, C_CH * 3);
        prepack_k3<<<dim3(6, L_N * FC_CH), blk, 0, stream>>>(f1w, Wf1, C_CH * 3);
        prepack_k3<<<dim3(24, L_N * C_CH), blk, 0, stream>>>(f2w, Wf2, FC_CH * 3);
        n = L_N * 1536 * 512;  prepack_qkv<<<(n + 255) / 256, blk, 0, stream>>>(qw, kw, vw, qb, kb, vb, Wqkv, Bqkv);
    }

    // ---- prologue ----
    transpose_f0<<<dim3(64, 16, B_SZ), blk, 0, stream>>>(x, xT, C_CH, nf0, f0w, f0b, 1);
    transpose_f0<<<dim3(64, 8, B_SZ), blk, 0, stream>>>(spk, spkT, S_CH, nullptr, nullptr, nullptr, 0);
    conv_gemm_mfma<1, 1, 64><<<gC64, blk, 0, stream>>>(spkT, Wcnd, cb, xT, xm, t0h, nullptr, S_CH, C_CH, 0, 0, 0, 0);
    conv_gemm_mfma<3, 1, 64><<<gC64, blk, 0, stream>>>(t0h, Wpre, prb, nullptr, xm, xbuf, nullptr, C_CH, C_CH, 1, 0, 0, 1);

    for (int l = 0; l < L_N; ++l) {
        const size_t bo = (size_t)l * C_CH;
        conv_gemm_mfma<1, 3, 64><<<gQKV, blk, 0, stream>>>(xbuf, Wqkv + (size_t)l * 1536 * 512, Bqkv + l * 1536,
                                                           nullptr, xm, qk, vt, C_CH, 1024, 0, 0, 0, 0);
        flash_attn_mfma<<<gAT, blk, 0, stream>>>(qk, vt, obf);
        conv_gemm_mfma<1, 1, 64><<<gC64, blk, 0, stream>>>(obf, Wo + (size_t)l * 512 * 512, ob + bo,
                                                           nullptr, xm, t0h, nullptr, C_CH, C_CH, 0, 0, 0, 0);
        ln_kernel<<<gLN, blk, 0, stream>>>(xbuf, t0h, ln0g + bo, ln0b + bo, xbuf);
        conv_gemm_mfma<3, 1, 64><<<gF, blk, 0, stream>>>(xbuf, Wf1 + (size_t)l * FC_CH * C_CH * 3, f1b + (size_t)l * FC_CH,
                                                         nullptr, xm, h1, nullptr, C_CH, FC_CH, 2, 1, 1, 0);
        conv_gemm_mfma<3, 1, 64><<<gC64, blk, 0, stream>>>(h1, Wf2 + (size_t)l * C_CH * FC_CH * 3, f2b + bo,
                                                           nullptr, xm, t0h, nullptr, FC_CH, C_CH, 2, 0, 1, 1);
        ln_kernel<<<gLN, blk, 0, stream>>>(xbuf, t0h, ln1g + bo, ln1b + bo, xbuf);
    }
    proj_kernel<<<gLN, blk, 0, stream>>>(xbuf, pjw, pjb, xm, out);
}

// Round 4
// 2166.696 us; speedup vs baseline: 1.0258x; 1.0258x over previous
//
#include <hip/hip_runtime.h>
#include <cstdint>
#include <cstddef>

#define T_LEN 2048
#define B_SZ 4
#define C_CH 512
#define H_N 8
#define DK_ 64
#define FC_CH 2048
#define L_N 6
#define KW 3
#define S_CH 256

typedef _Float16 h8 __attribute__((ext_vector_type(8)));
typedef _Float16 h4 __attribute__((ext_vector_type(4)));
typedef float floatx4 __attribute__((ext_vector_type(4)));

// ---------------------------------------------------------------------------
// Weight prepack kernels (run every call; weights -> f16 in ws).
// ---------------------------------------------------------------------------
__global__ __launch_bounds__(256)
void cast_f16(const float* __restrict__ src, _Float16* __restrict__ dst, int n)
{
    int i = blockIdx.x * 256 + threadIdx.x;
    if (i < n) dst[i] = (_Float16)src[i];
}

// src [row][c][k] (k fastest, K=3) -> dst [row][c0blk][k][cl] (32-ch chunks)
// 2D grid (col-chunk, row) so ALL divisors are compile-time consts.
__global__ __launch_bounds__(256)
void prepack_k3(const float* __restrict__ src, _Float16* __restrict__ dst, int rk)
{
    const int o = blockIdx.x * 256 + threadIdx.x;
    if (o >= rk) return;
    const size_t row = blockIdx.y;
    const int blk = o / 96, rr = o - blk * 96;   // 96 = const -> magic mul
    const int k = rr >> 5, cl = rr & 31;
    dst[row * rk + o] = (_Float16)src[row * rk + (size_t)(blk * 32 + cl) * 3 + k];
}

// concat q|k|v weights into [l][1536][512] f16 + biases into [l][1536] f32
__global__ __launch_bounds__(256)
void prepack_qkv(const float* __restrict__ qw, const float* __restrict__ kw,
                 const float* __restrict__ vw, const float* __restrict__ qb,
                 const float* __restrict__ kb, const float* __restrict__ vb,
                 _Float16* __restrict__ dst, float* __restrict__ bdst)
{
    int i = blockIdx.x * 256 + threadIdx.x;
    const int total = L_N * 1536 * 512;
    if (i < total) {
        int l = i / (1536 * 512);
        int o = i - l * (1536 * 512);
        int m = o >> 9, c = o & 511;
        const float* s = (m < 512) ? qw : ((m < 1024) ? kw : vw);
        dst[i] = (_Float16)s[((size_t)l * 512 + (m & 511)) * 512 + c];
    }
    if (i < L_N * 1536) {
        int l = i / 1536, m = i - l * 1536;
        const float* s = (m < 512) ? qb : ((m < 1024) ? kb : vb);
        bdst[i] = s[l * 512 + (m & 511)];
    }
}

// ---------------------------------------------------------------------------
// Transpose [b][Cd][T] -> f16 [b][T][Cd], optionally fusing the f0 conv add.
// ---------------------------------------------------------------------------
__global__ __launch_bounds__(256)
void transpose_f0(const float* __restrict__ src, _Float16* __restrict__ dst, int Cd,
                  const float* __restrict__ nf0, const float* __restrict__ f0w,
                  const float* __restrict__ f0b, int do_f0)
{
    __shared__ float tile[32][33];
    const int tl = threadIdx.x & 31;
    const int r  = threadIdx.x >> 5;
    const int t00 = blockIdx.x * 32;
    const int c00 = blockIdx.y * 32;
    const int b   = blockIdx.z;
    const float* s0 = src + (size_t)b * Cd * T_LEN;
#pragma unroll
    for (int rr = 0; rr < 4; ++rr) {
        int cl = r + rr * 8;
        tile[cl][tl] = s0[(size_t)(c00 + cl) * T_LEN + t00 + tl];
    }
    __syncthreads();
    _Float16* d0 = dst + (size_t)b * T_LEN * Cd;
    const int cg = c00 + tl;
#pragma unroll
    for (int rr = 0; rr < 4; ++rr) {
        int tlo = r + rr * 8;
        float v = tile[tl][tlo];
        if (do_f0) {
            int tg = t00 + tlo;
            float a = f0b[cg];
#pragma unroll
            for (int k = 0; k < 3; ++k) {
                int gt = tg + k - 1;
                if (gt >= 0 && gt < T_LEN) a += f0w[cg * 3 + k] * nf0[(size_t)b * T_LEN + gt];
            }
            v += a;
        }
        d0[(size_t)(t00 + tlo) * Cd + cg] = (_Float16)v;
    }
}

// ---------------------------------------------------------------------------
// Conv1d-as-GEMM on MFMA, prepacked f16 weights, f16 activations.
//
// Round-11 per-site config (round-10 post-mortem: MT=64 hurts FLOP/LDS-read
// ratio — wave 64Mx64T reads 8 frags -> 16 MFMAs (ratio 2.0) vs 32Mx64T
// 6 -> 8 (1.33); LDS pipe is the binding resource at MfmaUtil 20%):
//   * DBUF=0, MT=128: single-buffer, 2 barriers/chunk — for sites with
//     plenty of blocks (ffn1 1024, QKV 768): best LDS ratio, 3-4 blocks/CU.
//   * DBUF=1, MT=64: double-buffered LDS, ONE barrier/chunk — for M=512
//     sites that would otherwise run 1 block/CU. Sec-0 ds_reads issue
//     BEFORE stage ds_writes (in-order lgkm retirement: sec-0 MFMAs don't
//     wait for the writes).
//
// Register pipeline: A 1-deep prefetch (areg), B 2-deep with statically-
// named breg0/breg1 (round-7 lesson: runtime-indexed register array demotes
// to scratch, ~13x; LDS buffer index pb is only an address offset — safe).
// All call sites have even nch >= 4.
//
// OUTMODE: 1 = f16 [b][t][out_stride] (+res); 3 = fused QKV (m0<1024 -> out_v
// stride 1024; m0>=1024 -> out2 transposed [b][m-1024][t]).
// ---------------------------------------------------------------------------
template<int KK, int OUTMODE, int MT, int DBUF>
__global__ __launch_bounds__(256)
void conv_gemm_mfma(const _Float16* __restrict__ in, const _Float16* __restrict__ Wpk,
                    const float* __restrict__ bias, const _Float16* __restrict__ res,
                    const float* __restrict__ mask, _Float16* __restrict__ out_v,
                    _Float16* __restrict__ out2,
                    int Cin, int out_stride, int pl, int do_relu,
                    int mask_in, int mask_out)
{
    constexpr int CS   = (KK == 3) ? 32 : 64;   // channels per chunk
    constexpr int NSEC = (KK == 3) ? 3 : 2;     // 32-wide A sections
    constexpr int AST  = NSEC * 32 + 8;         // 104 / 72 halves
    constexpr int HALO = (KK == 3) ? 2 : 0;
    constexpr int RB   = 128 + 2 * HALO;
    constexpr int BST  = CS + 8;                // 40 / 72 halves
    constexpr int NAH  = NSEC * MT / 64;        // A h8-regs per thread
    constexpr int SEGW = NSEC * MT / 8;         // A halves per staging segment
    constexpr int IM_N = MT / 32;               // acc M-frags per wave
    constexpr int NTASK = RB * (CS / 16);       // B 16-half tasks
    constexpr int NBUF = DBUF + 1;
    __shared__ _Float16 sA[NBUF][MT * AST];
    __shared__ _Float16 sB[NBUF][RB * BST];

    const int tid = threadIdx.x;
    const int lane = tid & 63;
    const int wid = tid >> 6;
    const int wm = wid >> 1, wt = wid & 1;
    const int r = lane & 15, q4 = lane >> 4;
    const int t0 = blockIdx.x * 128;
    const int m0 = blockIdx.y * MT;
    const int b  = blockIdx.z;
    const float* mk = mask + (size_t)b * T_LEN;

    floatx4 acc[IM_N][4];
#pragma unroll
    for (int i = 0; i < IM_N; ++i)
#pragma unroll
        for (int j = 0; j < 4; ++j)
#pragma unroll
            for (int c = 0; c < 4; ++c) acc[i][j][c] = 0.f;

    // ---- A staging assignment (bank pattern matches verified rounds) ----
    const int arow = tid & (MT - 1);
    const int ah0  = (tid / MT) * SEGW;
    const _Float16* ap = Wpk + (size_t)(m0 + arow) * Cin * KK + ah0;

    // ---- B task decode (chunk-invariant) ----
    int brw[2], bcc[2];
    bool bex[2], bval[2];
    _Float16 bm[2];
    const _Float16* bq[2];
    h8 areg[NAH], breg0[2][2], breg1[2][2];   // [task][half], buffers statically named
#pragma unroll
    for (int t2 = 0; t2 < 2; ++t2) {
        const int id = tid + t2 * 256;
        bex[t2] = (id < NTASK);
        int row, c16;
        if (KK == 3) { row = id % RB; c16 = (id / RB) * 16; }
        else         { row = id >> 2; c16 = (id & 3) * 16; }
        const int gt = t0 + row - HALO;
        bval[t2] = bex[t2] && gt >= 0 && gt < T_LEN;
        brw[t2] = row; bcc[t2] = c16;
        bm[t2] = (_Float16)((bval[t2] && mask_in) ? mk[gt] : 1.f);
        bq[t2] = in + (size_t)b * T_LEN * Cin + (size_t)gt * Cin + c16;
#pragma unroll
        for (int hh = 0; hh < 2; ++hh)
#pragma unroll
            for (int j = 0; j < 8; ++j) {
                breg0[t2][hh][j] = (_Float16)0.f;
                breg1[t2][hh][j] = (_Float16)0.f;
            }
    }
    const int nch = Cin / CS;   // even, >= 4, for all call sites

    // helpers (all fully inlined; static unrolls inside)
    auto loadA = [&]() {                 // areg <- next A chunk
        ap += CS * KK;
#pragma unroll
        for (int j = 0; j < NAH; ++j) areg[j] = *reinterpret_cast<const h8*>(ap + j * 8);
    };
    auto loadB = [&](h8 (&br)[2][2]) {   // br <- next B chunk (2-deep queue)
#pragma unroll
        for (int t2 = 0; t2 < 2; ++t2)
            if (bval[t2]) {
                br[t2][0] = *reinterpret_cast<const h8*>(bq[t2]);
                br[t2][1] = *reinterpret_cast<const h8*>(bq[t2] + 8);
                bq[t2] += CS;
            }
    };
    auto stage = [&](int pb, h8 (&br)[2][2]) {   // regs -> LDS buf pb
#pragma unroll
        for (int j = 0; j < NAH; ++j)
            *reinterpret_cast<h8*>(&sA[pb][arow * AST + ah0 + j * 8]) = areg[j];
#pragma unroll
        for (int t2 = 0; t2 < 2; ++t2)
            if (bex[t2]) {
                *reinterpret_cast<h8*>(&sB[pb][brw[t2] * BST + bcc[t2]]) = br[t2][0] * bm[t2];
                *reinterpret_cast<h8*>(&sB[pb][brw[t2] * BST + bcc[t2] + 8]) = br[t2][1] * bm[t2];
            }
    };

    // ---- prologue: A(0)->areg, B(0)->breg0, B(1)->breg1 ----
#pragma unroll
    for (int j = 0; j < NAH; ++j) areg[j] = *reinterpret_cast<const h8*>(ap + j * 8);
#pragma unroll
    for (int t2 = 0; t2 < 2; ++t2)
        if (bval[t2]) {
            breg0[t2][0] = *reinterpret_cast<const h8*>(bq[t2]);
            breg0[t2][1] = *reinterpret_cast<const h8*>(bq[t2] + 8);
            breg1[t2][0] = *reinterpret_cast<const h8*>(bq[t2] + CS);
            breg1[t2][1] = *reinterpret_cast<const h8*>(bq[t2] + CS + 8);
            bq[t2] += 2 * CS;
        }

    if constexpr (DBUF == 1) {
        // ---- double-buffered: ONE barrier per chunk ----
        stage(0, breg0);             // chunk 0 -> buf0 (no barrier needed first)
        loadA();                     // areg = A(1)
        loadB(breg0);                // breg0 = B(2)
        __syncthreads();             // buf0 ready

        // compute chunk cc from buf pb; stage chunk cc+1 into buf pb^1;
        // prefetch A(cc+2), B(cc+3)->br. Sec-0 reads issued before writes.
        auto body = [&](int pb, int cc, h8 (&br)[2][2]) {
            h8 af0[IM_N], bf0[4];
#pragma unroll
            for (int im = 0; im < IM_N; ++im)
                af0[im] = *reinterpret_cast<const h8*>(&sA[pb][(wm * (MT / 2) + im * 16 + r) * AST + q4 * 8]);
            {
                const int rb0 = (KK == 3) ? (wt * 64 + r - pl + HALO) : (wt * 64 + r);
#pragma unroll
                for (int jt = 0; jt < 4; ++jt)
                    bf0[jt] = *reinterpret_cast<const h8*>(&sB[pb][(rb0 + jt * 16) * BST + q4 * 8]);
            }
            if (cc + 1 < nch) stage(pb ^ 1, br);
            if (cc + 2 < nch) loadA();
            if (cc + 3 < nch) loadB(br);
#pragma unroll
            for (int im = 0; im < IM_N; ++im)
#pragma unroll
                for (int jt = 0; jt < 4; ++jt)
                    acc[im][jt] = __builtin_amdgcn_mfma_f32_16x16x32_f16(af0[im], bf0[jt], acc[im][jt], 0, 0, 0);
#pragma unroll
            for (int sec = 1; sec < NSEC; ++sec) {
                h8 af[IM_N], bf[4];
#pragma unroll
                for (int im = 0; im < IM_N; ++im)
                    af[im] = *reinterpret_cast<const h8*>(&sA[pb][(wm * (MT / 2) + im * 16 + r) * AST + sec * 32 + q4 * 8]);
                const int rb0 = (KK == 3) ? (wt * 64 + r + sec - pl + HALO) : (wt * 64 + r);
                const int cb0 = (KK == 3) ? 0 : sec * 32;
#pragma unroll
                for (int jt = 0; jt < 4; ++jt)
                    bf[jt] = *reinterpret_cast<const h8*>(&sB[pb][(rb0 + jt * 16) * BST + cb0 + q4 * 8]);
#pragma unroll
                for (int im = 0; im < IM_N; ++im)
#pragma unroll
                    for (int jt = 0; jt < 4; ++jt)
                        acc[im][jt] = __builtin_amdgcn_mfma_f32_16x16x32_f16(af[im], bf[jt], acc[im][jt], 0, 0, 0);
            }
            __syncthreads();
        };

        for (int ci = 0; ci < nch; ci += 2) {
            body(0, ci, breg1);      // chunk ci   (even -> buf0; stages odd)
            body(1, ci + 1, breg0);  // chunk ci+1 (odd -> buf1; stages even)
        }
    } else {
        // ---- single-buffer: 2 barriers per chunk (best LDS-read ratio at
        // MT=128; used where grid gives >= 3 blocks/CU) ----
        auto run_chunk = [&](h8 (&br)[2][2], int ci) {
            __syncthreads();
            stage(0, br);
            __syncthreads();
            if (ci + 1 < nch) loadA();
            if (ci + 2 < nch) loadB(br);
#pragma unroll
            for (int sec = 0; sec < NSEC; ++sec) {
                h8 af[IM_N], bf[4];
#pragma unroll
                for (int im = 0; im < IM_N; ++im)
                    af[im] = *reinterpret_cast<const h8*>(&sA[0][(wm * (MT / 2) + im * 16 + r) * AST + sec * 32 + q4 * 8]);
                const int rb0 = (KK == 3) ? (wt * 64 + r + sec - pl + HALO) : (wt * 64 + r);
                const int cb0 = (KK == 3) ? 0 : sec * 32;
#pragma unroll
                for (int jt = 0; jt < 4; ++jt)
                    bf[jt] = *reinterpret_cast<const h8*>(&sB[0][(rb0 + jt * 16) * BST + cb0 + q4 * 8]);
#pragma unroll
                for (int im = 0; im < IM_N; ++im)
#pragma unroll
                    for (int jt = 0; jt < 4; ++jt)
                        acc[im][jt] = __builtin_amdgcn_mfma_f32_16x16x32_f16(af[im], bf[jt], acc[im][jt], 0, 0, 0);
            }
        };

        for (int ci = 0; ci < nch; ci += 2) {
            run_chunk(breg0, ci);
            run_chunk(breg1, ci + 1);
        }
    }

    // ---- epilogue: D row = m (q4*4+reg), col = t (r) ----
#pragma unroll
    for (int im = 0; im < IM_N; ++im) {
        const int mb = m0 + wm * (MT / 2) + im * 16 + q4 * 4;
        const float4 bv = *reinterpret_cast<const float4*>(&bias[mb]);
#pragma unroll
        for (int jt = 0; jt < 4; ++jt) {
            const int t = t0 + wt * 64 + jt * 16 + r;
            float vv[4];
            vv[0] = acc[im][jt][0] + bv.x;
            vv[1] = acc[im][jt][1] + bv.y;
            vv[2] = acc[im][jt][2] + bv.z;
            vv[3] = acc[im][jt][3] + bv.w;
            if (do_relu) {
#pragma unroll
                for (int c = 0; c < 4; ++c) vv[c] = fmaxf(vv[c], 0.f);
            }
            if (mask_out) {
                const float mv = mk[t];
#pragma unroll
                for (int c = 0; c < 4; ++c) vv[c] *= mv;
            }
            if (OUTMODE == 1) {
                const size_t ob = ((size_t)b * T_LEN + t) * out_stride + mb;
                if (res) {
                    const h4 rv = *reinterpret_cast<const h4*>(&res[ob]);
#pragma unroll
                    for (int c = 0; c < 4; ++c) vv[c] += (float)rv[c];
                }
                h4 hv;
#pragma unroll
                for (int c = 0; c < 4; ++c) hv[c] = (_Float16)vv[c];
                *reinterpret_cast<h4*>(&out_v[ob]) = hv;
            } else {   // fused QKV
                if (m0 < 1024) {
                    const size_t ob = ((size_t)b * T_LEN + t) * 1024 + mb;
                    h4 hv;
#pragma unroll
                    for (int c = 0; c < 4; ++c) hv[c] = (_Float16)vv[c];
                    *reinterpret_cast<h4*>(&out_v[ob]) = hv;
                } else {
#pragma unroll
                    for (int reg = 0; reg < 4; ++reg)
                        out2[((size_t)b * C_CH + (mb - 1024) + reg) * T_LEN + t] = (_Float16)vv[reg];
                }
            }
        }
    }
}

// ---------------------------------------------------------------------------
// MFMA flash attention with ONLINE softmax (p <= 1, f16-safe).
// qk: [b][t][1024] f16 (q|k); vt: [b][h*64+d][t] f16; o: [b][t][512] f16.
// Q-tile 64, swapped QK^T (lane-resident softmax rows), h4 P stores.
// blockIdx.x reversed: longest (qt0 max) first.
// ---------------------------------------------------------------------------
__global__ __launch_bounds__(256)
void flash_attn_mfma(const _Float16* __restrict__ qk, const _Float16* __restrict__ vt,
                     _Float16* __restrict__ o)
{
    __shared__ _Float16 sK[64 * 72];    // [s][d]
    __shared__ _Float16 sVt[64 * 72];   // [d][s]
    __shared__ _Float16 sP[64 * 72];    // [q][s]
    const int tid = threadIdx.x;
    const int lane = tid & 63;
    const int w = tid >> 6;             // wave w owns q rows qt0+w*16 .. +15
    const int r = lane & 15, q4 = lane >> 4;
    const int qt0 = (int)(31 - blockIdx.x) * 64;
    const int h = blockIdx.y, b = blockIdx.z;
    const size_t tb = (size_t)b * T_LEN;
    const int hq = h * 64, hk = 512 + h * 64;
    const _Float16* vbase = vt + ((size_t)b * C_CH + h * 64) * T_LEN;

    // Q fragment (B-operand: lane holds col n=r -> q-row qt0+w*16+r, k=q4*8+j)
    h8 qf[2];
#pragma unroll
    for (int dc = 0; dc < 2; ++dc) {
        h8 t = *reinterpret_cast<const h8*>(
            &qk[(tb + qt0 + w * 16 + r) * 1024 + hq + dc * 32 + q4 * 8]);
        qf[dc] = t * (_Float16)0.125f;
    }

    floatx4 oacc[4];
    float mrow = -__builtin_inff();     // running max for q-row qt0+w*16+r
    float lrow = 0.f;                   // running sum for q-row qt0+w*16+r
#pragma unroll
    for (int jd = 0; jd < 4; ++jd)
#pragma unroll
        for (int c = 0; c < 4; ++c) oacc[jd][c] = 0.f;

    const int qg = qt0 + w * 16 + r;    // this lane's q-row (for mask + softmax)
    const int nk = (qt0 >> 6) + 1;
    for (int kt = 0; kt < nk; ++kt) {
        const int kt0 = kt * 64;
        __syncthreads();
        {   // stage K tile [64 s][64 d]
            int row = tid >> 2, c16 = (tid & 3) * 16;
            const _Float16* src = &qk[(tb + kt0 + row) * 1024 + hk + c16];
            *reinterpret_cast<h8*>(&sK[row * 72 + c16]) = *reinterpret_cast<const h8*>(src);
            *reinterpret_cast<h8*>(&sK[row * 72 + c16 + 8]) = *reinterpret_cast<const h8*>(src + 8);
        }
#pragma unroll
        for (int p = 0; p < 2; ++p) {   // stage V^T tile [64 d][64 s]
            int id = p * 256 + tid;
            int d = id >> 3, s8 = (id & 7) * 8;
            *reinterpret_cast<h8*>(&sVt[d * 72 + s8]) =
                *reinterpret_cast<const h8*>(&vbase[(size_t)d * T_LEN + kt0 + s8]);
        }
        __syncthreads();

        // ---- QK^T (swapped): sacc[js] holds D[s=kt0+js*16+q4*4+reg][q=qg]
        floatx4 sacc[4];
#pragma unroll
        for (int js = 0; js < 4; ++js)
#pragma unroll
            for (int c = 0; c < 4; ++c) sacc[js][c] = 0.f;
#pragma unroll
        for (int dc = 0; dc < 2; ++dc) {
            h8 kf[4];
#pragma unroll
            for (int js = 0; js < 4; ++js)
                kf[js] = *reinterpret_cast<const h8*>(&sK[(js * 16 + r) * 72 + dc * 32 + q4 * 8]);
#pragma unroll
            for (int js = 0; js < 4; ++js)
                sacc[js] = __builtin_amdgcn_mfma_f32_16x16x32_f16(kf[js], qf[dc], sacc[js], 0, 0, 0);
        }
        // ---- causal mask (s > q -> -1e4, matches reference where())
#pragma unroll
        for (int js = 0; js < 4; ++js) {
            const int sb = kt0 + js * 16 + q4 * 4;
#pragma unroll
            for (int reg = 0; reg < 4; ++reg)
                if (sb + reg > qg) sacc[js][reg] = -1e4f;
        }
        // ---- row max: 16 in-register values, then cross-q4-group reduce
        float mt;
        {
            float a = fmaxf(fmaxf(sacc[0][0], sacc[0][1]), fmaxf(sacc[0][2], sacc[0][3]));
            float bm = fmaxf(fmaxf(sacc[1][0], sacc[1][1]), fmaxf(sacc[1][2], sacc[1][3]));
            float c = fmaxf(fmaxf(sacc[2][0], sacc[2][1]), fmaxf(sacc[2][2], sacc[2][3]));
            float d = fmaxf(fmaxf(sacc[3][0], sacc[3][1]), fmaxf(sacc[3][2], sacc[3][3]));
            mt = fmaxf(fmaxf(a, bm), fmaxf(c, d));
        }
        mt = fmaxf(mt, __shfl_xor(mt, 16));
        mt = fmaxf(mt, __shfl_xor(mt, 32));
        const float mn = fmaxf(mrow, mt);
        const float alpha = __expf(mrow - mn);
        mrow = mn;
        // ---- P = exp(s - mn), in-register row sum
        float rs = 0.f;
#pragma unroll
        for (int js = 0; js < 4; ++js)
#pragma unroll
            for (int reg = 0; reg < 4; ++reg) {
                float p = __expf(sacc[js][reg] - mn);
                sacc[js][reg] = p;
                rs += p;
            }
        rs += __shfl_xor(rs, 16);
        rs += __shfl_xor(rs, 32);
        lrow = lrow * alpha + rs;
        // ---- rescale O accumulator (row layout q = w*16 + q4*4 + reg)
        float ao[4];
#pragma unroll
        for (int reg = 0; reg < 4; ++reg) ao[reg] = __shfl(alpha, (q4 << 2) + reg, 16);
#pragma unroll
        for (int jd = 0; jd < 4; ++jd)
#pragma unroll
            for (int reg = 0; reg < 4; ++reg) oacc[jd][reg] *= ao[reg];
        // ---- P -> LDS, vectorized h4 (regs are s-contiguous in swapped layout)
#pragma unroll
        for (int js = 0; js < 4; ++js) {
            h4 hv;
#pragma unroll
            for (int reg = 0; reg < 4; ++reg) hv[reg] = (_Float16)sacc[js][reg];
            *reinterpret_cast<h4*>(&sP[(w * 16 + r) * 72 + js * 16 + q4 * 4]) = hv;
        }
        // ---- PV: oacc[jd] += P[q][s] * V[s][d]   (same-wave sP reuse, no barrier)
#pragma unroll
        for (int sc = 0; sc < 2; ++sc) {
            h8 pf = *reinterpret_cast<const h8*>(&sP[(w * 16 + r) * 72 + sc * 32 + q4 * 8]);
            h8 vf[4];
#pragma unroll
            for (int jd = 0; jd < 4; ++jd)
                vf[jd] = *reinterpret_cast<const h8*>(&sVt[(jd * 16 + r) * 72 + sc * 32 + q4 * 8]);
#pragma unroll
            for (int jd = 0; jd < 4; ++jd)
                oacc[jd] = __builtin_amdgcn_mfma_f32_16x16x32_f16(pf, vf[jd], oacc[jd], 0, 0, 0);
        }
    }
    // ---- epilogue: O row q = qt0 + w*16 + q4*4 + reg, col d = jd*16 + r
    const float linv = 1.f / lrow;      // for q-row = qg (lane layout q=r)
    float li[4];
#pragma unroll
    for (int reg = 0; reg < 4; ++reg) li[reg] = __shfl(linv, (q4 << 2) + reg, 16);
#pragma unroll
    for (int reg = 0; reg < 4; ++reg) {
        const size_t rowb = (tb + qt0 + w * 16 + (q4 << 2) + reg) * 512 + h * 64 + r;
#pragma unroll
        for (int jd = 0; jd < 4; ++jd)
            o[rowb + jd * 16] = (_Float16)(oacc[jd][reg] * li[reg]);
    }
}

// ---------------------------------------------------------------------------
// Channel LayerNorm on f16 [b][t][512]: one wave per t-row. outx = LN(x+y)*g+be
// ---------------------------------------------------------------------------
__global__ __launch_bounds__(256)
void ln_kernel(const _Float16* __restrict__ x, const _Float16* __restrict__ y,
               const float* __restrict__ g, const float* __restrict__ be,
               _Float16* __restrict__ outx)
{
    const int w = threadIdx.x >> 6, lane = threadIdx.x & 63;
    const int t = blockIdx.x * 4 + w, b = blockIdx.y;
    const size_t base = ((size_t)b * T_LEN + t) * C_CH + lane * 8;
    h8 xv = *reinterpret_cast<const h8*>(&x[base]);
    h8 yv = *reinterpret_cast<const h8*>(&y[base]);
    float v[8];
#pragma unroll
    for (int i = 0; i < 8; ++i) v[i] = (float)xv[i] + (float)yv[i];
    float s = 0.f, s2 = 0.f;
#pragma unroll
    for (int i = 0; i < 8; ++i) { s += v[i]; s2 += v[i] * v[i]; }
#pragma unroll
    for (int off = 1; off < 64; off <<= 1) {
        s  += __shfl_xor(s, off);
        s2 += __shfl_xor(s2, off);
    }
    const float mean = s * (1.f / C_CH);
    const float var  = s2 * (1.f / C_CH) - mean * mean;
    const float rstd = rsqrtf(var + 1e-5f);
    float4 g0 = *reinterpret_cast<const float4*>(&g[lane * 8]);
    float4 g1 = *reinterpret_cast<const float4*>(&g[lane * 8 + 4]);
    float4 b0 = *reinterpret_cast<const float4*>(&be[lane * 8]);
    float4 b1 = *reinterpret_cast<const float4*>(&be[lane * 8 + 4]);
    const float gg[8] = {g0.x, g0.y, g0.z, g0.w, g1.x, g1.y, g1.z, g1.w};
    const float bb[8] = {b0.x, b0.y, b0.z, b0.w, b1.x, b1.y, b1.z, b1.w};
    h8 ov;
#pragma unroll
    for (int i = 0; i < 8; ++i)
        ov[i] = (_Float16)((v[i] - mean) * rstd * gg[i] + bb[i]);
    *reinterpret_cast<h8*>(&outx[base]) = ov;
}

// out[b,t] = ( mask * sum_c pw[c]*x[b,t,c] + pb ) * mask   (one wave per t)
__global__ __launch_bounds__(256)
void proj_kernel(const _Float16* __restrict__ x, const float* __restrict__ pw,
                 const float* __restrict__ pb, const float* __restrict__ mask,
                 float* __restrict__ out)
{
    const int w = threadIdx.x >> 6, lane = threadIdx.x & 63;
    const int t = blockIdx.x * 4 + w, b = blockIdx.y;
    const size_t base = ((size_t)b * T_LEN + t) * C_CH + lane * 8;
    h8 xv = *reinterpret_cast<const h8*>(&x[base]);
    float4 p0 = *reinterpret_cast<const float4*>(&pw[lane * 8]);
    float4 p1 = *reinterpret_cast<const float4*>(&pw[lane * 8 + 4]);
    const float pp[8] = {p0.x, p0.y, p0.z, p0.w, p1.x, p1.y, p1.z, p1.w};
    float s = 0.f;
#pragma unroll
    for (int i = 0; i < 8; ++i) s += (float)xv[i] * pp[i];
#pragma unroll
    for (int off = 1; off < 64; off <<= 1) s += __shfl_xor(s, off);
    if (lane == 0) {
        const float mv = mask[(size_t)b * T_LEN + t];
        out[(size_t)b * T_LEN + t] = (s * mv + pb[0]) * mv;
    }
}

extern "C" void kernel_launch(void* const* d_in, const int* in_sizes, int n_in,
                              void* d_out, int out_size, void* d_ws, size_t ws_size,
                              hipStream_t stream)
{
    const float* x    = (const float*)d_in[0];
    const float* nf0  = (const float*)d_in[1];
    const float* xm   = (const float*)d_in[2];
    const float* spk  = (const float*)d_in[3];
    const float* prw  = (const float*)d_in[4];
    const float* prb  = (const float*)d_in[5];
    const float* f0w  = (const float*)d_in[6];
    const float* f0b  = (const float*)d_in[7];
    const float* cw   = (const float*)d_in[8];
    const float* cb   = (const float*)d_in[9];
    const float* pjw  = (const float*)d_in[10];
    const float* pjb  = (const float*)d_in[11];
    const float* qw   = (const float*)d_in[12];
    const float* qb   = (const float*)d_in[13];
    const float* kw   = (const float*)d_in[14];
    const float* kb   = (const float*)d_in[15];
    const float* vw   = (const float*)d_in[16];
    const float* vb   = (const float*)d_in[17];
    const float* ow   = (const float*)d_in[18];
    const float* ob   = (const float*)d_in[19];
    const float* ln0g = (const float*)d_in[20];
    const float* ln0b = (const float*)d_in[21];
    const float* ln1g = (const float*)d_in[22];
    const float* ln1b = (const float*)d_in[23];
    const float* f1w  = (const float*)d_in[24];
    const float* f1b  = (const float*)d_in[25];
    const float* f2w  = (const float*)d_in[26];
    const float* f2b  = (const float*)d_in[27];
    float* out = (float*)d_out;

    const size_t NCT = (size_t)B_SZ * C_CH * T_LEN;
    char* wp = (char*)d_ws;
    _Float16* xbuf = (_Float16*)wp; wp += NCT * 2;            // [b][t][512] residual
    _Float16* t0h  = (_Float16*)wp; wp += NCT * 2;            // [b][t][512] sublayer out
    _Float16* qk   = (_Float16*)wp; wp += NCT * 4;            // [b][t][1024]
    _Float16* vt   = (_Float16*)wp; wp += NCT * 2;            // [b][h*64+d][t]
    _Float16* obf  = (_Float16*)wp; wp += NCT * 2;            // [b][t][512]
    _Float16* h1   = (_Float16*)wp; wp += NCT * 8;            // [b][t][2048]
    _Float16* xT   = h1;                                       // alias (dead before h1 use)
    _Float16* spkT = obf;                                      // alias (dead before obf use)
    _Float16* Wqkv = (_Float16*)wp; wp += (size_t)L_N * 1536 * 512 * 2;
    _Float16* Wo   = (_Float16*)wp; wp += (size_t)L_N * 512 * 512 * 2;
    _Float16* Wcnd = (_Float16*)wp; wp += (size_t)512 * 256 * 2;
    _Float16* Wpre = (_Float16*)wp; wp += (size_t)512 * 512 * 3 * 2;
    _Float16* Wf1  = (_Float16*)wp; wp += (size_t)L_N * 2048 * 512 * 3 * 2;
    _Float16* Wf2  = (_Float16*)wp; wp += (size_t)L_N * 512 * 2048 * 3 * 2;
    float*    Bqkv = (float*)wp;    wp += (size_t)L_N * 1536 * 4;

    dim3 blk(256);
    dim3 gC64(16, 8, B_SZ);     // M=512 convs, MT=64 dbuf
    dim3 gQKV(16, 12, B_SZ);    // M=1536 fused QKV, MT=128 single
    dim3 gF(16, 16, B_SZ);      // M=2048 ffn1, MT=128 single
    dim3 gAT(32, H_N, B_SZ);    // flash, Q-tile 64
    dim3 gLN(T_LEN / 4, B_SZ);

    // ---- weight prepack ----
    {
        int n;
        n = C_CH * S_CH;       cast_f16<<<(n + 255) / 256, blk, 0, stream>>>(cw, Wcnd, n);
        n = L_N * C_CH * C_CH; cast_f16<<<(n + 255) / 256, blk, 0, stream>>>(ow, Wo, n);
        prepack_k3<<<dim3(6, C_CH), blk, 0, stream>>>(prw, Wpre, C_CH * 3);
        prepack_k3<<<dim3(6, L_N * FC_CH), blk, 0, stream>>>(f1w, Wf1, C_CH * 3);
        prepack_k3<<<dim3(24, L_N * C_CH), blk, 0, stream>>>(f2w, Wf2, FC_CH * 3);
        n = L_N * 1536 * 512;  prepack_qkv<<<(n + 255) / 256, blk, 0, stream>>>(qw, kw, vw, qb, kb, vb, Wqkv, Bqkv);
    }

    // ---- prologue ----
    transpose_f0<<<dim3(64, 16, B_SZ), blk, 0, stream>>>(x, xT, C_CH, nf0, f0w, f0b, 1);
    transpose_f0<<<dim3(64, 8, B_SZ), blk, 0, stream>>>(spk, spkT, S_CH, nullptr, nullptr, nullptr, 0);
    conv_gemm_mfma<1, 1, 64, 1><<<gC64, blk, 0, stream>>>(spkT, Wcnd, cb, xT, xm, t0h, nullptr, S_CH, C_CH, 0, 0, 0, 0);
    conv_gemm_mfma<3, 1, 64, 1><<<gC64, blk, 0, stream>>>(t0h, Wpre, prb, nullptr, xm, xbuf, nullptr, C_CH, C_CH, 1, 0, 0, 1);

    for (int l = 0; l < L_N; ++l) {
        const size_t bo = (size_t)l * C_CH;
        conv_gemm_mfma<1, 3, 128, 0><<<gQKV, blk, 0, stream>>>(xbuf, Wqkv + (size_t)l * 1536 * 512, Bqkv + l * 1536,
                                                               nullptr, xm, qk, vt, C_CH, 1024, 0, 0, 0, 0);
        flash_attn_mfma<<<gAT, blk, 0, stream>>>(qk, vt, obf);
        conv_gemm_mfma<1, 1, 64, 1><<<gC64, blk, 0, stream>>>(obf, Wo + (size_t)l * 512 * 512, ob + bo,
                                                              nullptr, xm, t0h, nullptr, C_CH, C_CH, 0, 0, 0, 0);
        ln_kernel<<<gLN, blk, 0, stream>>>(xbuf, t0h, ln0g + bo, ln0b + bo, xbuf);
        conv_gemm_mfma<3, 1, 128, 0><<<gF, blk, 0, stream>>>(xbuf, Wf1 + (size_t)l * FC_CH * C_CH * 3, f1b + (size_t)l * FC_CH,
                                                             nullptr, xm, h1, nullptr, C_CH, FC_CH, 2, 1, 1, 0);
        conv_gemm_mfma<3, 1, 64, 1><<<gC64, blk, 0, stream>>>(h1, Wf2 + (size_t)l * C_CH * FC_CH * 3, f2b + bo,
                                                              nullptr, xm, t0h, nullptr, FC_CH, C_CH, 2, 0, 1, 1);
        ln_kernel<<<gLN, blk, 0, stream>>>(xbuf, t0h, ln1g + bo, ln1b + bo, xbuf);
    }
    proj_kernel<<<gLN, blk, 0, stream>>>(xbuf, pjw, pjb, xm, out);
}